// Round 1
// baseline (102.318 us; speedup 1.0000x reference)
//
#include <hip/hip_runtime.h>
#include <cstdint>

// ---------------------------------------------------------------------------
// QuantumBranch, R4: single fused kernel, zero barriers.
// R3 post-mortem: two serialized launches (1-wave setup kernel = whole-GPU
// bubble) + a block-wide __syncthreads (vmcnt drain) that synchronized all
// 4 blocks/CU into compute-then-store-burst phases. Store floor is
// 64 MiB / ~6 TB/s = 11 us; the burst ran mostly serial after compute.
//
// R4: every wave redundantly computes the setup (weights are uniform, so
// all waves derive identical V / LN constants), parks V^T + constants in a
// PER-WAVE LDS region (wave-local coherence -> lgkmcnt only, no barrier),
// and owns its own 64 samples end-to-end: phase-1 circuit per lane, then
// phase-2 coalesced stores with q/inv broadcast via intra-wave __shfl.
// Stores issue as soon as each wave finishes -> drain overlaps other
// waves' VALU work. Arithmetic association kept IDENTICAL to R3
// (absmax is exactly at 0.015625; do not perturb rounding).
//
// Math (verified R1-R3): circuit collapses to V = U*diag((-i)^popc),
// z_w = sum_i +/- (r_i^2+s_i^2), r=Re(V)m, s=Im(V)m, m = product-state
// magnitudes from tanh(x)*pi/2. LayerNorm collapses to a 4x4 quadratic
// form: out[b,k] = inv_b*(A[k].q_b + B0[k]) + beta[k].
// ---------------------------------------------------------------------------

// per-wave LDS region float offsets
#define WS_VRT 0     // 256: Re(V)^T  [col*16+row]
#define WS_VIT 256   // 256: Im(V)^T
#define WS_A   512   // 256: (W-colmean)*gamma  [k*4+w]
#define WS_B0  768   // 64:  (b-bmean)*gamma
#define WS_G   832   // 16:  G[4][4]
#define WS_g   848   // 4
#define WS_C0  852   // 1
#define WREG   864   // padded region size (16B aligned)

__global__ __launch_bounds__(256) void qb_fused(const float* __restrict__ x,
                                                const float* __restrict__ wts,
                                                const float* __restrict__ W,
                                                const float* __restrict__ bias,
                                                const float* __restrict__ gamma,
                                                const float* __restrict__ beta,
                                                float* __restrict__ out) {
    __shared__ __align__(16) float lds[4 * WREG];
    const int tid  = threadIdx.x;
    const int wv   = tid >> 6;
    const int lane = tid & 63;
    float* wlds = lds + wv * WREG;

    // issue x load first: HBM latency hides under the setup compute
    const int sample = blockIdx.x * 256 + tid;
    const float4 xv = ((const float4*)x)[sample];

    // ---- per-wave redundant setup (identical across waves; wave-local LDS) ----
    {
        const int row = lane >> 2;
        const int cg  = lane & 3;
        float ur[4], ui[4];   // U[row][4cg+c]
        #pragma unroll
        for (int c = 0; c < 4; ++c) { ur[c] = (row == 4*cg + c) ? 1.f : 0.f; ui[c] = 0.f; }

        #pragma unroll
        for (int l = 0; l < 2; ++l) {
            #pragma unroll
            for (int w = 0; w < 4; ++w) {
                const float ph = wts[l*12 + w*3 + 0];
                const float th = wts[l*12 + w*3 + 1];
                const float om = wts[l*12 + w*3 + 2];
                float st, ct; __sincosf(0.5f*th, &st, &ct);
                float sp, cp; __sincosf(0.5f*(ph+om), &sp, &cp);
                float sm, cm; __sincosf(0.5f*(ph-om), &sm, &cm);
                const float a00r =  cp*ct, a00i = -sp*ct;
                const float a01r = -cm*st, a01i = -sm*st;
                const float a10r =  cm*st, a10i = -sm*st;
                const float a11r =  cp*ct, a11i =  sp*ct;
                const int m8 = 8 >> w;
                const int xm = m8 << 2;           // lane xor mask for row^m8
                const bool hi = (row & m8) != 0;
                #pragma unroll
                for (int c = 0; c < 4; ++c) {
                    const float pr = __shfl_xor(ur[c], xm, 64);
                    const float pi = __shfl_xor(ui[c], xm, 64);
                    float nr, ni;
                    if (!hi) {
                        nr = a00r*ur[c] - a00i*ui[c] + a01r*pr - a01i*pi;
                        ni = a00r*ui[c] + a00i*ur[c] + a01r*pi + a01i*pr;
                    } else {
                        nr = a11r*ur[c] - a11i*ui[c] + a10r*pr - a10i*pi;
                        ni = a11r*ui[c] + a11i*ur[c] + a10r*pi + a10i*pr;
                    }
                    ur[c] = nr; ui[c] = ni;
                }
            }
            const int rr = (l == 0) ? 1 : 2;
            #pragma unroll
            for (int w = 0; w < 4; ++w) {
                const int cmk = 8 >> w;
                const int tmk = 8 >> ((w + rr) & 3);
                const int src = (row & cmk) ? (row ^ tmk) : row;
                const int srcLane = src*4 + cg;
                #pragma unroll
                for (int c = 0; c < 4; ++c) {
                    ur[c] = __shfl(ur[c], srcLane, 64);
                    ui[c] = __shfl(ui[c], srcLane, 64);
                }
            }
        }

        // V = U * diag((-i)^popc(col)); park transposed in this wave's region
        #pragma unroll
        for (int c = 0; c < 4; ++c) {
            const int col = 4*cg + c;
            const int p = __popc(col) & 3;
            float vr, vi;
            if (p == 0)      { vr =  ur[c]; vi =  ui[c]; }
            else if (p == 1) { vr =  ui[c]; vi = -ur[c]; }
            else if (p == 2) { vr = -ur[c]; vi = -ui[c]; }
            else             { vr = -ui[c]; vi =  ur[c]; }
            wlds[WS_VRT + col*16 + row] = vr;
            wlds[WS_VIT + col*16 + row] = vi;
        }

        // projection / layernorm constants: k = lane (PROJ_DIM=64 = 1 wave)
        {
            const int k = lane;
            const float4 wk = ((const float4*)W)[k];
            const float w0 = wk.x, w1 = wk.y, w2 = wk.z, w3 = wk.w;
            const float bk = bias[k];
            auto wsum = [](float v) {
                #pragma unroll
                for (int o = 32; o; o >>= 1) v += __shfl_xor(v, o, 64);
                return v;
            };
            const float inv64 = 1.f/64.f;
            const float m0 = wsum(w0)*inv64, m1 = wsum(w1)*inv64;
            const float m2 = wsum(w2)*inv64, m3 = wsum(w3)*inv64;
            const float bm = wsum(bk)*inv64;
            float cc[4] = {w0-m0, w1-m1, w2-m2, w3-m3};
            const float bc = bk - bm;
            const float gk = gamma[k];
            float4 av;
            av.x = cc[0]*gk; av.y = cc[1]*gk; av.z = cc[2]*gk; av.w = cc[3]*gk;
            ((float4*)(wlds + WS_A))[k] = av;
            wlds[WS_B0 + k] = bc*gk;
            #pragma unroll
            for (int a = 0; a < 4; ++a)
                #pragma unroll
                for (int b2 = 0; b2 < 4; ++b2) {
                    const float s = wsum(cc[a]*cc[b2])*inv64;   // wave-uniform result
                    if (k == 0) wlds[WS_G + a*4 + b2] = s;
                }
            #pragma unroll
            for (int a = 0; a < 4; ++a) {
                const float s = wsum(bc*cc[a])*inv64;
                if (k == 0) wlds[WS_g + a] = s;
            }
            { const float s = wsum(bc*bc)*inv64; if (k == 0) wlds[WS_C0] = s; }
        }
    }
    // NO __syncthreads: all LDS traffic is within this wave's private region.

    // ---- phase 1: per-sample circuit -> q, inv ----
    const float xa[4] = {xv.x, xv.y, xv.z, xv.w};
    float c4[4], s4[4];
    #pragma unroll
    for (int w = 0; w < 4; ++w) {
        const float h = tanhf(xa[w]) * 1.5707963267948966f;
        __sincosf(h, &s4[w], &c4[w]);
    }
    const float e01[4] = {c4[0]*c4[1], c4[0]*s4[1], s4[0]*c4[1], s4[0]*s4[1]};
    const float e23[4] = {c4[2]*c4[3], c4[2]*s4[3], s4[2]*c4[3], s4[2]*s4[3]};
    float m[16];
    #pragma unroll
    for (int j = 0; j < 16; ++j) m[j] = e01[j>>2]*e23[j&3];

    float r[16], si[16];
    #pragma unroll
    for (int i = 0; i < 16; ++i) { r[i] = 0.f; si[i] = 0.f; }
    const float4* vr4 = (const float4*)(wlds + WS_VRT);
    const float4* vi4 = (const float4*)(wlds + WS_VIT);
    #pragma unroll
    for (int j = 0; j < 16; ++j) {
        const float mj = m[j];
        #pragma unroll
        for (int i4 = 0; i4 < 4; ++i4) {
            const float4 a = vr4[j*4 + i4];   // uniform-address broadcast ds_read_b128
            const float4 b = vi4[j*4 + i4];
            r [i4*4+0] = fmaf(a.x, mj, r [i4*4+0]);
            r [i4*4+1] = fmaf(a.y, mj, r [i4*4+1]);
            r [i4*4+2] = fmaf(a.z, mj, r [i4*4+2]);
            r [i4*4+3] = fmaf(a.w, mj, r [i4*4+3]);
            si[i4*4+0] = fmaf(b.x, mj, si[i4*4+0]);
            si[i4*4+1] = fmaf(b.y, mj, si[i4*4+1]);
            si[i4*4+2] = fmaf(b.z, mj, si[i4*4+2]);
            si[i4*4+3] = fmaf(b.w, mj, si[i4*4+3]);
        }
    }
    float z0 = 0.f, z1 = 0.f, z2 = 0.f, z3 = 0.f;
    #pragma unroll
    for (int i = 0; i < 16; ++i) {
        const float p = r[i]*r[i] + si[i]*si[i];
        z0 += (i & 8) ? -p : p;
        z1 += (i & 4) ? -p : p;
        z2 += (i & 2) ? -p : p;
        z3 += (i & 1) ? -p : p;
    }
    const float mx = fmaxf(fmaxf(z0, z1), fmaxf(z2, z3));
    const float e0 = __expf(z0-mx), e1 = __expf(z1-mx);
    const float e2 = __expf(z2-mx), e3 = __expf(z3-mx);
    const float rs = 1.f / (e0+e1+e2+e3);
    const float qx = e0*rs, qy = e1*rs, qz = e2*rs, qw = e3*rs;

    float var = wlds[WS_C0];
    {
        const float4 Gs0 = ((const float4*)(wlds + WS_G))[0];
        const float4 Gs1 = ((const float4*)(wlds + WS_G))[1];
        const float4 Gs2 = ((const float4*)(wlds + WS_G))[2];
        const float4 Gs3 = ((const float4*)(wlds + WS_G))[3];
        const float4 gv  = ((const float4*)(wlds + WS_g))[0];
        const float qa[4] = {qx, qy, qz, qw};
        const float4 Gs[4] = {Gs0, Gs1, Gs2, Gs3};
        const float ga[4] = {gv.x, gv.y, gv.z, gv.w};
        #pragma unroll
        for (int a = 0; a < 4; ++a) {
            float t = 2.f * ga[a];
            t = fmaf(Gs[a].x, qa[0], t);
            t = fmaf(Gs[a].y, qa[1], t);
            t = fmaf(Gs[a].z, qa[2], t);
            t = fmaf(Gs[a].w, qa[3], t);
            var = fmaf(qa[a], t, var);
        }
    }
    const float inv = rsqrtf(var + 1e-5f);

    // ---- phase 2: wave-local coalesced stores, q/inv via shfl broadcast ----
    const int k4t = lane & 15;
    float4 A4[4];
    #pragma unroll
    for (int u = 0; u < 4; ++u) A4[u] = ((const float4*)(wlds + WS_A))[k4t*4 + u];
    const float4 B04v = ((const float4*)(wlds + WS_B0))[k4t];
    const float4 Bt4v = ((const float4*)beta)[k4t];
    const float B04[4] = {B04v.x, B04v.y, B04v.z, B04v.w};
    const float Bt4[4] = {Bt4v.x, Bt4v.y, Bt4v.z, Bt4v.w};

    // wave wv owns samples [block*256 + wv*64, +64): 16 KB contiguous
    float4* outv = (float4*)out + (size_t)blockIdx.x * 4096 + wv * 1024;
    #pragma unroll
    for (int iter = 0; iter < 16; ++iter) {
        const int src = iter*4 + (lane >> 4);       // producing lane of sample
        const float bqx = __shfl(qx,  src, 64);
        const float bqy = __shfl(qy,  src, 64);
        const float bqz = __shfl(qz,  src, 64);
        const float bqw = __shfl(qw,  src, 64);
        const float biv = __shfl(inv, src, 64);
        float4 o;
        float* op = (float*)&o;
        #pragma unroll
        for (int u = 0; u < 4; ++u) {
            float t = B04[u];
            t = fmaf(A4[u].x, bqx, t);
            t = fmaf(A4[u].y, bqy, t);
            t = fmaf(A4[u].z, bqz, t);
            t = fmaf(A4[u].w, bqw, t);
            op[u] = fmaf(t, biv, Bt4[u]);
        }
        outv[iter*64 + lane] = o;
    }
}

extern "C" void kernel_launch(void* const* d_in, const int* in_sizes, int n_in,
                              void* d_out, int out_size, void* d_ws, size_t ws_size,
                              hipStream_t stream) {
    const float* x     = (const float*)d_in[0];
    const float* wts   = (const float*)d_in[1];
    const float* W     = (const float*)d_in[2];
    const float* bias  = (const float*)d_in[3];
    const float* gamma = (const float*)d_in[4];
    const float* beta  = (const float*)d_in[5];
    float* out = (float*)d_out;
    const int B = in_sizes[0] / 4;   // 262144

    hipLaunchKernelGGL(qb_fused, dim3(B / 256), dim3(256), 0, stream,
                       x, wts, W, bias, gamma, beta, out);
}

// Round 2
// 95.059 us; speedup vs baseline: 1.0764x; 1.0764x over previous
//
#include <hip/hip_runtime.h>
#include <cstdint>

// ---------------------------------------------------------------------------
// QuantumBranch, R5: fused kernel, per-BLOCK setup (wave 0) + one barrier.
// R4 post-mortem: per-WAVE redundant setup (~280 shfl + 24 sincos per wave,
// x4 waves/SIMD) cost ~+5us chip-wide — more than the ~3us launch-bubble it
// removed (measured 97.0 -> 102.3). R5 amortizes setup per block (4x less),
// hides it behind hoisted x-dependent work (m[16], beta load issued before
// the barrier), and trims the setup critical path via G-symmetry (10
// wave-sums instead of 16). Barrier is BEFORE compute, so no store-burst
// lockstep; store phase stays barrier-free via intra-wave shfl broadcast.
//
// Math (verified R1-R4): circuit collapses to V = U*diag((-i)^popc),
// z_w = sum_i +/- (r_i^2+s_i^2), r=Re(V)m, s=Im(V)m, m = product-state
// magnitudes from tanh(x)*pi/2. LayerNorm collapses to a 4x4 quadratic
// form: out[b,k] = inv_b*(A[k].q_b + B0[k]) + beta[k].
// Arithmetic association kept IDENTICAL (absmax sits exactly at 0.015625).
// ---------------------------------------------------------------------------

// block-shared LDS float offsets
#define WS_VRT 0     // 256: Re(V)^T  [col*16+row]
#define WS_VIT 256   // 256: Im(V)^T
#define WS_A   512   // 256: (W-colmean)*gamma  [k*4+w]
#define WS_B0  768   // 64:  (b-bmean)*gamma
#define WS_G   832   // 16:  G[4][4]
#define WS_g   848   // 4
#define WS_C0  852   // 1
#define WREG   864   // padded size (16B aligned)

__global__ __launch_bounds__(256) void qb_fused(const float* __restrict__ x,
                                                const float* __restrict__ wts,
                                                const float* __restrict__ W,
                                                const float* __restrict__ bias,
                                                const float* __restrict__ gamma,
                                                const float* __restrict__ beta,
                                                float* __restrict__ out) {
    __shared__ __align__(16) float wlds[WREG];
    const int tid  = threadIdx.x;
    const int wv   = tid >> 6;
    const int lane = tid & 63;

    // issue x load first: HBM latency hides under pre-barrier compute
    const int sample = blockIdx.x * 256 + tid;
    const float4 xv = ((const float4*)x)[sample];

    // beta for the store phase: independent of setup, issue before barrier
    const int k4t = lane & 15;
    const float4 Bt4v = ((const float4*)beta)[k4t];

    // ---- pre-barrier: x-dependent product-state magnitudes m[16] ----
    float m[16];
    {
        const float xa[4] = {xv.x, xv.y, xv.z, xv.w};
        float c4[4], s4[4];
        #pragma unroll
        for (int w = 0; w < 4; ++w) {
            const float h = tanhf(xa[w]) * 1.5707963267948966f;
            __sincosf(h, &s4[w], &c4[w]);
        }
        const float e01[4] = {c4[0]*c4[1], c4[0]*s4[1], s4[0]*c4[1], s4[0]*s4[1]};
        const float e23[4] = {c4[2]*c4[3], c4[2]*s4[3], s4[2]*c4[3], s4[2]*s4[3]};
        #pragma unroll
        for (int j = 0; j < 16; ++j) m[j] = e01[j>>2]*e23[j&3];
    }

    // ---- wave 0 only: setup -> block-shared LDS ----
    if (wv == 0) {
        const int row = lane >> 2;
        const int cg  = lane & 3;
        float ur[4], ui[4];   // U[row][4cg+c]
        #pragma unroll
        for (int c = 0; c < 4; ++c) { ur[c] = (row == 4*cg + c) ? 1.f : 0.f; ui[c] = 0.f; }

        #pragma unroll
        for (int l = 0; l < 2; ++l) {
            #pragma unroll
            for (int w = 0; w < 4; ++w) {
                const float ph = wts[l*12 + w*3 + 0];
                const float th = wts[l*12 + w*3 + 1];
                const float om = wts[l*12 + w*3 + 2];
                float st, ct; __sincosf(0.5f*th, &st, &ct);
                float sp, cp; __sincosf(0.5f*(ph+om), &sp, &cp);
                float sm, cm; __sincosf(0.5f*(ph-om), &sm, &cm);
                const float a00r =  cp*ct, a00i = -sp*ct;
                const float a01r = -cm*st, a01i = -sm*st;
                const float a10r =  cm*st, a10i = -sm*st;
                const float a11r =  cp*ct, a11i =  sp*ct;
                const int m8 = 8 >> w;
                const int xm = m8 << 2;           // lane xor mask for row^m8
                const bool hi = (row & m8) != 0;
                #pragma unroll
                for (int c = 0; c < 4; ++c) {
                    const float pr = __shfl_xor(ur[c], xm, 64);
                    const float pi = __shfl_xor(ui[c], xm, 64);
                    float nr, ni;
                    if (!hi) {
                        nr = a00r*ur[c] - a00i*ui[c] + a01r*pr - a01i*pi;
                        ni = a00r*ui[c] + a00i*ur[c] + a01r*pi + a01i*pr;
                    } else {
                        nr = a11r*ur[c] - a11i*ui[c] + a10r*pr - a10i*pi;
                        ni = a11r*ui[c] + a11i*ur[c] + a10r*pi + a10i*pr;
                    }
                    ur[c] = nr; ui[c] = ni;
                }
            }
            const int rr = (l == 0) ? 1 : 2;
            #pragma unroll
            for (int w = 0; w < 4; ++w) {
                const int cmk = 8 >> w;
                const int tmk = 8 >> ((w + rr) & 3);
                const int src = (row & cmk) ? (row ^ tmk) : row;
                const int srcLane = src*4 + cg;
                #pragma unroll
                for (int c = 0; c < 4; ++c) {
                    ur[c] = __shfl(ur[c], srcLane, 64);
                    ui[c] = __shfl(ui[c], srcLane, 64);
                }
            }
        }

        // V = U * diag((-i)^popc(col)); park transposed in block LDS
        #pragma unroll
        for (int c = 0; c < 4; ++c) {
            const int col = 4*cg + c;
            const int p = __popc(col) & 3;
            float vr, vi;
            if (p == 0)      { vr =  ur[c]; vi =  ui[c]; }
            else if (p == 1) { vr =  ui[c]; vi = -ur[c]; }
            else if (p == 2) { vr = -ur[c]; vi = -ui[c]; }
            else             { vr = -ui[c]; vi =  ur[c]; }
            wlds[WS_VRT + col*16 + row] = vr;
            wlds[WS_VIT + col*16 + row] = vi;
        }

        // projection / layernorm constants: k = lane (PROJ_DIM=64 = 1 wave)
        {
            const int k = lane;
            const float4 wk = ((const float4*)W)[k];
            const float w0 = wk.x, w1 = wk.y, w2 = wk.z, w3 = wk.w;
            const float bk = bias[k];
            auto wsum = [](float v) {
                #pragma unroll
                for (int o = 32; o; o >>= 1) v += __shfl_xor(v, o, 64);
                return v;
            };
            const float inv64 = 1.f/64.f;
            const float m0 = wsum(w0)*inv64, m1 = wsum(w1)*inv64;
            const float m2 = wsum(w2)*inv64, m3 = wsum(w3)*inv64;
            const float bm = wsum(bk)*inv64;
            float cc[4] = {w0-m0, w1-m1, w2-m2, w3-m3};
            const float bc = bk - bm;
            const float gk = gamma[k];
            float4 av;
            av.x = cc[0]*gk; av.y = cc[1]*gk; av.z = cc[2]*gk; av.w = cc[3]*gk;
            ((float4*)(wlds + WS_A))[k] = av;
            wlds[WS_B0 + k] = bc*gk;
            // G is symmetric: 10 wave-sums instead of 16
            #pragma unroll
            for (int a = 0; a < 4; ++a)
                #pragma unroll
                for (int b2 = a; b2 < 4; ++b2) {
                    const float s = wsum(cc[a]*cc[b2])*inv64;   // wave-uniform
                    if (k == 0) {
                        wlds[WS_G + a*4 + b2] = s;
                        wlds[WS_G + b2*4 + a] = s;
                    }
                }
            #pragma unroll
            for (int a = 0; a < 4; ++a) {
                const float s = wsum(bc*cc[a])*inv64;
                if (k == 0) wlds[WS_g + a] = s;
            }
            { const float s = wsum(bc*bc)*inv64; if (k == 0) wlds[WS_C0] = s; }
        }
    }

    __syncthreads();   // the ONLY barrier: setup results now block-visible

    // ---- phase 1: matvec from LDS (uniform-address broadcast reads) ----
    float r[16], si[16];
    #pragma unroll
    for (int i = 0; i < 16; ++i) { r[i] = 0.f; si[i] = 0.f; }
    const float4* vr4 = (const float4*)(wlds + WS_VRT);
    const float4* vi4 = (const float4*)(wlds + WS_VIT);
    #pragma unroll
    for (int j = 0; j < 16; ++j) {
        const float mj = m[j];
        #pragma unroll
        for (int i4 = 0; i4 < 4; ++i4) {
            const float4 a = vr4[j*4 + i4];
            const float4 b = vi4[j*4 + i4];
            r [i4*4+0] = fmaf(a.x, mj, r [i4*4+0]);
            r [i4*4+1] = fmaf(a.y, mj, r [i4*4+1]);
            r [i4*4+2] = fmaf(a.z, mj, r [i4*4+2]);
            r [i4*4+3] = fmaf(a.w, mj, r [i4*4+3]);
            si[i4*4+0] = fmaf(b.x, mj, si[i4*4+0]);
            si[i4*4+1] = fmaf(b.y, mj, si[i4*4+1]);
            si[i4*4+2] = fmaf(b.z, mj, si[i4*4+2]);
            si[i4*4+3] = fmaf(b.w, mj, si[i4*4+3]);
        }
    }
    float z0 = 0.f, z1 = 0.f, z2 = 0.f, z3 = 0.f;
    #pragma unroll
    for (int i = 0; i < 16; ++i) {
        const float p = r[i]*r[i] + si[i]*si[i];
        z0 += (i & 8) ? -p : p;
        z1 += (i & 4) ? -p : p;
        z2 += (i & 2) ? -p : p;
        z3 += (i & 1) ? -p : p;
    }
    const float mx = fmaxf(fmaxf(z0, z1), fmaxf(z2, z3));
    const float e0 = __expf(z0-mx), e1 = __expf(z1-mx);
    const float e2 = __expf(z2-mx), e3 = __expf(z3-mx);
    const float rs = 1.f / (e0+e1+e2+e3);
    const float qx = e0*rs, qy = e1*rs, qz = e2*rs, qw = e3*rs;

    float var = wlds[WS_C0];
    {
        const float4 Gs0 = ((const float4*)(wlds + WS_G))[0];
        const float4 Gs1 = ((const float4*)(wlds + WS_G))[1];
        const float4 Gs2 = ((const float4*)(wlds + WS_G))[2];
        const float4 Gs3 = ((const float4*)(wlds + WS_G))[3];
        const float4 gv  = ((const float4*)(wlds + WS_g))[0];
        const float qa[4] = {qx, qy, qz, qw};
        const float4 Gs[4] = {Gs0, Gs1, Gs2, Gs3};
        const float ga[4] = {gv.x, gv.y, gv.z, gv.w};
        #pragma unroll
        for (int a = 0; a < 4; ++a) {
            float t = 2.f * ga[a];
            t = fmaf(Gs[a].x, qa[0], t);
            t = fmaf(Gs[a].y, qa[1], t);
            t = fmaf(Gs[a].z, qa[2], t);
            t = fmaf(Gs[a].w, qa[3], t);
            var = fmaf(qa[a], t, var);
        }
    }
    const float inv = rsqrtf(var + 1e-5f);

    // ---- phase 2: wave-local coalesced stores, q/inv via shfl broadcast ----
    float4 A4[4];
    #pragma unroll
    for (int u = 0; u < 4; ++u) A4[u] = ((const float4*)(wlds + WS_A))[k4t*4 + u];
    const float4 B04v = ((const float4*)(wlds + WS_B0))[k4t];
    const float B04[4] = {B04v.x, B04v.y, B04v.z, B04v.w};
    const float Bt4[4] = {Bt4v.x, Bt4v.y, Bt4v.z, Bt4v.w};

    // wave wv owns samples [block*256 + wv*64, +64): 16 KB contiguous
    float4* outv = (float4*)out + (size_t)blockIdx.x * 4096 + wv * 1024;
    #pragma unroll
    for (int iter = 0; iter < 16; ++iter) {
        const int src = iter*4 + (lane >> 4);       // producing lane of sample
        const float bqx = __shfl(qx,  src, 64);
        const float bqy = __shfl(qy,  src, 64);
        const float bqz = __shfl(qz,  src, 64);
        const float bqw = __shfl(qw,  src, 64);
        const float biv = __shfl(inv, src, 64);
        float4 o;
        float* op = (float*)&o;
        #pragma unroll
        for (int u = 0; u < 4; ++u) {
            float t = B04[u];
            t = fmaf(A4[u].x, bqx, t);
            t = fmaf(A4[u].y, bqy, t);
            t = fmaf(A4[u].z, bqz, t);
            t = fmaf(A4[u].w, bqw, t);
            op[u] = fmaf(t, biv, Bt4[u]);
        }
        outv[iter*64 + lane] = o;
    }
}

extern "C" void kernel_launch(void* const* d_in, const int* in_sizes, int n_in,
                              void* d_out, int out_size, void* d_ws, size_t ws_size,
                              hipStream_t stream) {
    const float* x     = (const float*)d_in[0];
    const float* wts   = (const float*)d_in[1];
    const float* W     = (const float*)d_in[2];
    const float* bias  = (const float*)d_in[3];
    const float* gamma = (const float*)d_in[4];
    const float* beta  = (const float*)d_in[5];
    float* out = (float*)d_out;
    const int B = in_sizes[0] / 4;   // 262144

    hipLaunchKernelGGL(qb_fused, dim3(B / 256), dim3(256), 0, stream,
                       x, wts, W, bias, gamma, beta, out);
}

// Round 3
// 92.512 us; speedup vs baseline: 1.1060x; 1.0275x over previous
//
#include <hip/hip_runtime.h>
#include <cstdint>

// ---------------------------------------------------------------------------
// QuantumBranch, R6: fused kernel; setup split across waves; LDS-staged
// store broadcast; VGPR cap.
// R5 post-mortem (95.06us, beat R3's 97.0): per-block setup amortization
// worked. Remaining inefficiencies attacked here:
//  (1) setup critical path was wave0-serial (unitary ~500 inst + LN ~350):
//      split -> wave0 = unitary, wave1 = LN constants, concurrent.
//  (2) store phase used 80 ds_bpermute/wave (5 per iter, latency chain
//      before each store): replaced with wave-local LDS staging of q/inv
//      (2 writes + 32 broadcast reads, immediate-offset ds_read_b128).
//      No barrier needed: same-wave LDS RAW is ordered by lgkmcnt (the
//      mechanism R4 validated).
//  (3) post-barrier live set ~110-130 VGPR, right at the 128 cliff where
//      residency halves (4 -> 2 blocks/CU): pinned with launch_bounds(256,4).
//
// Math (verified R1-R5): circuit collapses to V = U*diag((-i)^popc),
// z_w = sum_i +/- (r_i^2+s_i^2), r=Re(V)m, s=Im(V)m, m = product-state
// magnitudes from tanh(x)*pi/2. LayerNorm collapses to a 4x4 quadratic
// form: out[b,k] = inv_b*(A[k].q_b + B0[k]) + beta[k].
// Arithmetic association kept IDENTICAL (absmax sits exactly at 0.015625).
// ---------------------------------------------------------------------------

// block-shared LDS float offsets
#define WS_VRT 0     // 256: Re(V)^T  [col*16+row]
#define WS_VIT 256   // 256: Im(V)^T
#define WS_A   512   // 256: (W-colmean)*gamma  [k*4+w]
#define WS_B0  768   // 64:  (b-bmean)*gamma
#define WS_G   832   // 16:  G[4][4]
#define WS_g   848   // 4
#define WS_C0  852   // 1
#define WS_Q   864   // 1024: staged q (float4 per sample), 4 waves x 64
#define WS_INV 1888  // 256:  staged inv, 4 waves x 64
#define WREG   2144  // total floats (8576 B)

__global__ __launch_bounds__(256, 4) void qb_fused(const float* __restrict__ x,
                                                   const float* __restrict__ wts,
                                                   const float* __restrict__ W,
                                                   const float* __restrict__ bias,
                                                   const float* __restrict__ gamma,
                                                   const float* __restrict__ beta,
                                                   float* __restrict__ out) {
    __shared__ __align__(16) float wlds[WREG];
    const int tid  = threadIdx.x;
    const int wv   = tid >> 6;
    const int lane = tid & 63;

    // issue x load first: HBM latency hides under pre-barrier compute
    const int sample = blockIdx.x * 256 + tid;
    const float4 xv = ((const float4*)x)[sample];

    // beta for the store phase: independent of setup, issue before barrier
    const int k4t = lane & 15;
    const float4 Bt4v = ((const float4*)beta)[k4t];

    // ---- pre-barrier: x-dependent product-state magnitudes m[16] ----
    float m[16];
    {
        const float xa[4] = {xv.x, xv.y, xv.z, xv.w};
        float c4[4], s4[4];
        #pragma unroll
        for (int w = 0; w < 4; ++w) {
            const float h = tanhf(xa[w]) * 1.5707963267948966f;
            __sincosf(h, &s4[w], &c4[w]);
        }
        const float e01[4] = {c4[0]*c4[1], c4[0]*s4[1], s4[0]*c4[1], s4[0]*s4[1]};
        const float e23[4] = {c4[2]*c4[3], c4[2]*s4[3], s4[2]*c4[3], s4[2]*s4[3]};
        #pragma unroll
        for (int j = 0; j < 16; ++j) m[j] = e01[j>>2]*e23[j&3];
    }

    // ---- wave 0: unitary -> V^T in block LDS ----
    if (wv == 0) {
        const int row = lane >> 2;
        const int cg  = lane & 3;
        float ur[4], ui[4];   // U[row][4cg+c]
        #pragma unroll
        for (int c = 0; c < 4; ++c) { ur[c] = (row == 4*cg + c) ? 1.f : 0.f; ui[c] = 0.f; }

        #pragma unroll
        for (int l = 0; l < 2; ++l) {
            #pragma unroll
            for (int w = 0; w < 4; ++w) {
                const float ph = wts[l*12 + w*3 + 0];
                const float th = wts[l*12 + w*3 + 1];
                const float om = wts[l*12 + w*3 + 2];
                float st, ct; __sincosf(0.5f*th, &st, &ct);
                float sp, cp; __sincosf(0.5f*(ph+om), &sp, &cp);
                float sm, cm; __sincosf(0.5f*(ph-om), &sm, &cm);
                const float a00r =  cp*ct, a00i = -sp*ct;
                const float a01r = -cm*st, a01i = -sm*st;
                const float a10r =  cm*st, a10i = -sm*st;
                const float a11r =  cp*ct, a11i =  sp*ct;
                const int m8 = 8 >> w;
                const int xm = m8 << 2;           // lane xor mask for row^m8
                const bool hi = (row & m8) != 0;
                #pragma unroll
                for (int c = 0; c < 4; ++c) {
                    const float pr = __shfl_xor(ur[c], xm, 64);
                    const float pi = __shfl_xor(ui[c], xm, 64);
                    float nr, ni;
                    if (!hi) {
                        nr = a00r*ur[c] - a00i*ui[c] + a01r*pr - a01i*pi;
                        ni = a00r*ui[c] + a00i*ur[c] + a01r*pi + a01i*pr;
                    } else {
                        nr = a11r*ur[c] - a11i*ui[c] + a10r*pr - a10i*pi;
                        ni = a11r*ui[c] + a11i*ur[c] + a10r*pi + a10i*pr;
                    }
                    ur[c] = nr; ui[c] = ni;
                }
            }
            const int rr = (l == 0) ? 1 : 2;
            #pragma unroll
            for (int w = 0; w < 4; ++w) {
                const int cmk = 8 >> w;
                const int tmk = 8 >> ((w + rr) & 3);
                const int src = (row & cmk) ? (row ^ tmk) : row;
                const int srcLane = src*4 + cg;
                #pragma unroll
                for (int c = 0; c < 4; ++c) {
                    ur[c] = __shfl(ur[c], srcLane, 64);
                    ui[c] = __shfl(ui[c], srcLane, 64);
                }
            }
        }

        // V = U * diag((-i)^popc(col)); park transposed in block LDS
        #pragma unroll
        for (int c = 0; c < 4; ++c) {
            const int col = 4*cg + c;
            const int p = __popc(col) & 3;
            float vr, vi;
            if (p == 0)      { vr =  ur[c]; vi =  ui[c]; }
            else if (p == 1) { vr =  ui[c]; vi = -ur[c]; }
            else if (p == 2) { vr = -ur[c]; vi = -ui[c]; }
            else             { vr = -ui[c]; vi =  ur[c]; }
            wlds[WS_VRT + col*16 + row] = vr;
            wlds[WS_VIT + col*16 + row] = vi;
        }
    } else if (wv == 1) {
        // ---- wave 1 (concurrent with wave 0): LN constants ----
        const int k = lane;
        const float4 wk = ((const float4*)W)[k];
        const float w0 = wk.x, w1 = wk.y, w2 = wk.z, w3 = wk.w;
        const float bk = bias[k];
        auto wsum = [](float v) {
            #pragma unroll
            for (int o = 32; o; o >>= 1) v += __shfl_xor(v, o, 64);
            return v;
        };
        const float inv64 = 1.f/64.f;
        const float m0 = wsum(w0)*inv64, m1 = wsum(w1)*inv64;
        const float m2 = wsum(w2)*inv64, m3 = wsum(w3)*inv64;
        const float bm = wsum(bk)*inv64;
        float cc[4] = {w0-m0, w1-m1, w2-m2, w3-m3};
        const float bc = bk - bm;
        const float gk = gamma[k];
        float4 av;
        av.x = cc[0]*gk; av.y = cc[1]*gk; av.z = cc[2]*gk; av.w = cc[3]*gk;
        ((float4*)(wlds + WS_A))[k] = av;
        wlds[WS_B0 + k] = bc*gk;
        // G is symmetric: 10 wave-sums instead of 16
        #pragma unroll
        for (int a = 0; a < 4; ++a)
            #pragma unroll
            for (int b2 = a; b2 < 4; ++b2) {
                const float s = wsum(cc[a]*cc[b2])*inv64;   // wave-uniform
                if (k == 0) {
                    wlds[WS_G + a*4 + b2] = s;
                    wlds[WS_G + b2*4 + a] = s;
                }
            }
        #pragma unroll
        for (int a = 0; a < 4; ++a) {
            const float s = wsum(bc*cc[a])*inv64;
            if (k == 0) wlds[WS_g + a] = s;
        }
        { const float s = wsum(bc*bc)*inv64; if (k == 0) wlds[WS_C0] = s; }
    }

    __syncthreads();   // the ONLY barrier: setup results now block-visible

    // ---- phase 1: matvec from LDS (uniform-address broadcast reads) ----
    float r[16], si[16];
    #pragma unroll
    for (int i = 0; i < 16; ++i) { r[i] = 0.f; si[i] = 0.f; }
    const float4* vr4 = (const float4*)(wlds + WS_VRT);
    const float4* vi4 = (const float4*)(wlds + WS_VIT);
    #pragma unroll
    for (int j = 0; j < 16; ++j) {
        const float mj = m[j];
        #pragma unroll
        for (int i4 = 0; i4 < 4; ++i4) {
            const float4 a = vr4[j*4 + i4];
            const float4 b = vi4[j*4 + i4];
            r [i4*4+0] = fmaf(a.x, mj, r [i4*4+0]);
            r [i4*4+1] = fmaf(a.y, mj, r [i4*4+1]);
            r [i4*4+2] = fmaf(a.z, mj, r [i4*4+2]);
            r [i4*4+3] = fmaf(a.w, mj, r [i4*4+3]);
            si[i4*4+0] = fmaf(b.x, mj, si[i4*4+0]);
            si[i4*4+1] = fmaf(b.y, mj, si[i4*4+1]);
            si[i4*4+2] = fmaf(b.z, mj, si[i4*4+2]);
            si[i4*4+3] = fmaf(b.w, mj, si[i4*4+3]);
        }
    }
    float z0 = 0.f, z1 = 0.f, z2 = 0.f, z3 = 0.f;
    #pragma unroll
    for (int i = 0; i < 16; ++i) {
        const float p = r[i]*r[i] + si[i]*si[i];
        z0 += (i & 8) ? -p : p;
        z1 += (i & 4) ? -p : p;
        z2 += (i & 2) ? -p : p;
        z3 += (i & 1) ? -p : p;
    }
    const float mx = fmaxf(fmaxf(z0, z1), fmaxf(z2, z3));
    const float e0 = __expf(z0-mx), e1 = __expf(z1-mx);
    const float e2 = __expf(z2-mx), e3 = __expf(z3-mx);
    const float rs = 1.f / (e0+e1+e2+e3);
    const float qx = e0*rs, qy = e1*rs, qz = e2*rs, qw = e3*rs;

    float var = wlds[WS_C0];
    {
        const float4 Gs0 = ((const float4*)(wlds + WS_G))[0];
        const float4 Gs1 = ((const float4*)(wlds + WS_G))[1];
        const float4 Gs2 = ((const float4*)(wlds + WS_G))[2];
        const float4 Gs3 = ((const float4*)(wlds + WS_G))[3];
        const float4 gv  = ((const float4*)(wlds + WS_g))[0];
        const float qa[4] = {qx, qy, qz, qw};
        const float4 Gs[4] = {Gs0, Gs1, Gs2, Gs3};
        const float ga[4] = {gv.x, gv.y, gv.z, gv.w};
        #pragma unroll
        for (int a = 0; a < 4; ++a) {
            float t = 2.f * ga[a];
            t = fmaf(Gs[a].x, qa[0], t);
            t = fmaf(Gs[a].y, qa[1], t);
            t = fmaf(Gs[a].z, qa[2], t);
            t = fmaf(Gs[a].w, qa[3], t);
            var = fmaf(qa[a], t, var);
        }
    }
    const float inv = rsqrtf(var + 1e-5f);

    // ---- stage q/inv in wave-local LDS (no barrier: same-wave RAW is
    //      ordered by lgkmcnt) ----
    ((float4*)(wlds + WS_Q))[wv*64 + lane] = make_float4(qx, qy, qz, qw);
    wlds[WS_INV + wv*64 + lane] = inv;

    // ---- phase 2: wave-local coalesced stores, q/inv via LDS broadcast ----
    float4 A4[4];
    #pragma unroll
    for (int u = 0; u < 4; ++u) A4[u] = ((const float4*)(wlds + WS_A))[k4t*4 + u];
    const float4 B04v = ((const float4*)(wlds + WS_B0))[k4t];
    const float B04[4] = {B04v.x, B04v.y, B04v.z, B04v.w};
    const float Bt4[4] = {Bt4v.x, Bt4v.y, Bt4v.z, Bt4v.w};

    // wave wv owns samples [block*256 + wv*64, +64): 16 KB contiguous
    float4* outv = (float4*)out + (size_t)blockIdx.x * 4096 + wv * 1024 + lane;
    const float4* qld = (const float4*)(wlds + WS_Q) + wv*64 + (lane >> 4);
    const float*  ild = wlds + WS_INV + wv*64 + (lane >> 4);
    #pragma unroll
    for (int iter = 0; iter < 16; ++iter) {
        const float4 q  = qld[iter*4];     // ds_read_b128, 4 addrs/wave, broadcast
        const float  iv = ild[iter*4];
        float4 o;
        float* op = (float*)&o;
        #pragma unroll
        for (int u = 0; u < 4; ++u) {
            float t = B04[u];
            t = fmaf(A4[u].x, q.x, t);
            t = fmaf(A4[u].y, q.y, t);
            t = fmaf(A4[u].z, q.z, t);
            t = fmaf(A4[u].w, q.w, t);
            op[u] = fmaf(t, iv, Bt4[u]);
        }
        outv[iter*64] = o;
    }
}

extern "C" void kernel_launch(void* const* d_in, const int* in_sizes, int n_in,
                              void* d_out, int out_size, void* d_ws, size_t ws_size,
                              hipStream_t stream) {
    const float* x     = (const float*)d_in[0];
    const float* wts   = (const float*)d_in[1];
    const float* W     = (const float*)d_in[2];
    const float* bias  = (const float*)d_in[3];
    const float* gamma = (const float*)d_in[4];
    const float* beta  = (const float*)d_in[5];
    float* out = (float*)d_out;
    const int B = in_sizes[0] / 4;   // 262144

    hipLaunchKernelGGL(qb_fused, dim3(B / 256), dim3(256), 0, stream,
                       x, wts, W, bias, gamma, beta, out);
}